// Round 3
// baseline (1197.071 us; speedup 1.0000x reference)
//
#include <hip/hip_runtime.h>

typedef __bf16 bf16;
typedef __bf16 bf16x8 __attribute__((ext_vector_type(8)));
typedef float f32x4 __attribute__((ext_vector_type(4)));

// ---------------------------------------------------------------------------
// Dtype detector: decide whether float tensors are bf16 (flag=0) or fp32
// (flag=1) by testing if low 16 bits of 64 words of rnn_feats look like
// plausible bf16 N(0,1) values. bf16 data: ~64/64 plausible. fp32 data:
// low half = random mantissa bits -> ~12% plausible.
// ---------------------------------------------------------------------------
__global__ void detect_k(const unsigned* __restrict__ rnn, int* __restrict__ flag) {
    const int lane = threadIdx.x;  // 64 threads
    const unsigned w = rnn[lane];
    const int e = (w >> 7) & 0xFF;               // exponent field of low half
    const bool good = (e >= 100 && e <= 130);    // |x| in [~1e-8, 16]
    const unsigned long long m = __ballot(good);
    if (lane == 0) *flag = (__popcll(m) >= 48) ? 0 : 1;
}

// ---------------------------------------------------------------------------
// Batched 64x64 tile transpose: in (B,R,C) [bf16 or fp32 per flag] ->
// out (B,C,R) bf16. grid = (C/64, R/64, B), 256 threads.
// ---------------------------------------------------------------------------
__global__ __launch_bounds__(256) void transpose_k(const void* __restrict__ in_,
                                                   bf16* __restrict__ out,
                                                   const int* __restrict__ flag,
                                                   int R, int C) {
    __shared__ __align__(16) bf16 t[64][72];
    const int dt = *flag;
    const long boff = (long)blockIdx.z * R * C;
    const int c0 = blockIdx.x * 64, r0 = blockIdx.y * 64;
    const int lr = threadIdx.x >> 2;          // 0..63
    const int lc = (threadIdx.x & 3) * 16;    // 0,16,32,48

    bf16x8 v0, v1;
    if (dt) {
        const float* src = (const float*)in_ + boff + (long)(r0 + lr) * C + c0 + lc;
        float4 f0 = ((const float4*)src)[0];
        float4 f1 = ((const float4*)src)[1];
        float4 f2 = ((const float4*)src)[2];
        float4 f3 = ((const float4*)src)[3];
        v0[0]=(bf16)f0.x; v0[1]=(bf16)f0.y; v0[2]=(bf16)f0.z; v0[3]=(bf16)f0.w;
        v0[4]=(bf16)f1.x; v0[5]=(bf16)f1.y; v0[6]=(bf16)f1.z; v0[7]=(bf16)f1.w;
        v1[0]=(bf16)f2.x; v1[1]=(bf16)f2.y; v1[2]=(bf16)f2.z; v1[3]=(bf16)f2.w;
        v1[4]=(bf16)f3.x; v1[5]=(bf16)f3.y; v1[6]=(bf16)f3.z; v1[7]=(bf16)f3.w;
    } else {
        const bf16* src = (const bf16*)in_ + boff + (long)(r0 + lr) * C + c0 + lc;
        v0 = ((const bf16x8*)src)[0];
        v1 = ((const bf16x8*)src)[1];
    }
    *(bf16x8*)(&t[lr][lc])     = v0;
    *(bf16x8*)(&t[lr][lc + 8]) = v1;
    __syncthreads();

    bf16 tmp[16];
#pragma unroll
    for (int k = 0; k < 16; ++k) tmp[k] = t[lc + k][lr];
    bf16* dst = out + boff + (long)(c0 + lr) * R + r0 + lc;
    *(float4*)(dst)     = *(float4*)(&tmp[0]);
    *(float4*)(dst + 8) = *(float4*)(&tmp[8]);
}

// ---------------------------------------------------------------------------
// 128x128 bf16-MFMA GEMM, BK=64, 256 threads (4 waves, 2x2 of 64x64,
// 4x4 mfma_f32_16x16x32_bf16 each). A: (M,K) row-major, dtype = flag if
// aIsInput else bf16. Bt: (N,K) row-major bf16 (ws). bias/W2: dtype = flag.
// XOR swizzle: LDS[row][c] = G[row][c ^ (row&7)] (chunk = 8 elems = 16B).
// EPI==0: C[m][n] = bf16(relu(acc + bias[n]))  (C always bf16, in ws)
// EPI==1: atomicAdd S[m][o] += sum_n relu(acc+bias[n])*W2[n][o]
// grid = (N/128, M/128, experts).
// ---------------------------------------------------------------------------
template <int EPI>
__global__ __launch_bounds__(256) void gemm128(const void* __restrict__ A_,
                                               const bf16* __restrict__ Bt,
                                               const void* __restrict__ bias_,
                                               const void* __restrict__ W2_,
                                               bf16* __restrict__ C,
                                               float* __restrict__ S,
                                               const int* __restrict__ flag,
                                               int aIsInput,
                                               int M, int N, int K) {
    __shared__ __align__(16) bf16 As[128 * 64];
    __shared__ __align__(16) bf16 Bs[128 * 64];

    const int dt = *flag;                 // input-tensor dtype: 0=bf16 1=fp32
    const int adt = aIsInput ? dt : 0;    // A dtype
    const long aesz = adt ? 4 : 2;
    const long besz = dt ? 4 : 2;         // bias/W2 element size

    const int tid = threadIdx.x;
    const int lane = tid & 63;
    const int wid = tid >> 6;
    const int wm = wid & 1, wn = wid >> 1;

    const int e = blockIdx.z;
    Bt += (long)e * N * K;
    const char* bias_b = (const char*)bias_ + (long)e * N * besz;
    const char* W2_b = nullptr;
    if constexpr (EPI == 1) {
        W2_b = (const char*)W2_ + (long)e * N * 2 * besz;
        S += (long)e * M * 2;
    }
    const int m0 = blockIdx.y * 128, n0 = blockIdx.x * 128;

    // staging: lane covers LDS rows srow + r*32, chunk lane&7 (8-elem chunks)
    const int srow = wid * 8 + (lane >> 3);               // + r*32
    const int scol = ((lane & 7) ^ (srow & 7)) * 8;       // swizzled source col
    const char* Ag = (const char*)A_ + ((long)(m0 + srow) * K + scol) * aesz;
    const bf16* Bg = Bt + (long)(n0 + srow) * K + scol;
    const int ldst = wid * 512 + lane * 8;                // + r*2048 (elems)

    f32x4 acc[4][4];
#pragma unroll
    for (int i = 0; i < 4; ++i)
#pragma unroll
        for (int j = 0; j < 4; ++j) acc[i][j] = (f32x4){0.f, 0.f, 0.f, 0.f};

    const int quad = lane >> 4;
    const int l15 = lane & 15;

    for (int k0 = 0; k0 < K; k0 += 64) {
        bf16x8 av[4], bv[4];
#pragma unroll
        for (int r = 0; r < 4; ++r) {
            const char* pa = Ag + ((long)(r * 32) * K + k0) * aesz;
            if (adt) {
                float4 f0 = ((const float4*)pa)[0];
                float4 f1 = ((const float4*)pa)[1];
                bf16x8 v;
                v[0]=(bf16)f0.x; v[1]=(bf16)f0.y; v[2]=(bf16)f0.z; v[3]=(bf16)f0.w;
                v[4]=(bf16)f1.x; v[5]=(bf16)f1.y; v[6]=(bf16)f1.z; v[7]=(bf16)f1.w;
                av[r] = v;
            } else {
                av[r] = *(const bf16x8*)pa;
            }
            bv[r] = *(const bf16x8*)(Bg + (long)(r * 32) * K + k0);
        }
        __syncthreads();
#pragma unroll
        for (int r = 0; r < 4; ++r) {
            *(bf16x8*)(As + r * 2048 + ldst) = av[r];
            *(bf16x8*)(Bs + r * 2048 + ldst) = bv[r];
        }
        __syncthreads();
#pragma unroll
        for (int kk = 0; kk < 2; ++kk) {
            bf16x8 af[4], bff[4];
            const int kc = kk * 4 + quad;  // 16B chunk within row
#pragma unroll
            for (int i = 0; i < 4; ++i) {
                const int m = wm * 64 + i * 16 + l15;
                af[i] = *(const bf16x8*)(As + m * 64 + (kc ^ (m & 7)) * 8);
                const int n = wn * 64 + i * 16 + l15;
                bff[i] = *(const bf16x8*)(Bs + n * 64 + (kc ^ (n & 7)) * 8);
            }
#pragma unroll
            for (int i = 0; i < 4; ++i)
#pragma unroll
                for (int j = 0; j < 4; ++j)
                    acc[i][j] = __builtin_amdgcn_mfma_f32_16x16x32_bf16(
                        af[i], bff[j], acc[i][j], 0, 0, 0);
        }
    }

    if constexpr (EPI == 0) {
#pragma unroll
        for (int j = 0; j < 4; ++j) {
            const int colg = n0 + wn * 64 + j * 16 + l15;
            const float bj = dt ? ((const float*)bias_b)[colg]
                                : (float)((const bf16*)bias_b)[colg];
#pragma unroll
            for (int i = 0; i < 4; ++i) {
                const int rowb = m0 + wm * 64 + i * 16 + quad * 4;
#pragma unroll
                for (int r = 0; r < 4; ++r) {
                    float v = acc[i][j][r] + bj;
                    v = v > 0.f ? v : 0.f;
                    C[(long)(rowb + r) * N + colg] = (bf16)v;
                }
            }
        }
    } else {
        float bj[4], w2f[4][2];
#pragma unroll
        for (int j = 0; j < 4; ++j) {
            const int colg = n0 + wn * 64 + j * 16 + l15;
            if (dt) {
                bj[j] = ((const float*)bias_b)[colg];
                w2f[j][0] = ((const float*)W2_b)[colg * 2 + 0];
                w2f[j][1] = ((const float*)W2_b)[colg * 2 + 1];
            } else {
                bj[j] = (float)((const bf16*)bias_b)[colg];
                w2f[j][0] = (float)((const bf16*)W2_b)[colg * 2 + 0];
                w2f[j][1] = (float)((const bf16*)W2_b)[colg * 2 + 1];
            }
        }
#pragma unroll
        for (int i = 0; i < 4; ++i) {
#pragma unroll
            for (int r = 0; r < 4; ++r) {
                float s0 = 0.f, s1 = 0.f;
#pragma unroll
                for (int j = 0; j < 4; ++j) {
                    float h = acc[i][j][r] + bj[j];
                    h = h > 0.f ? h : 0.f;
                    s0 += h * w2f[j][0];
                    s1 += h * w2f[j][1];
                }
#pragma unroll
                for (int msk = 1; msk < 16; msk <<= 1) {
                    s0 += __shfl_xor(s0, msk);
                    s1 += __shfl_xor(s1, msk);
                }
                if (l15 == 0) {
                    const int rowg = m0 + wm * 64 + i * 16 + quad * 4 + r;
                    atomicAdd(&S[rowg * 2 + 0], s0);
                    atomicAdd(&S[rowg * 2 + 1], s1);
                }
            }
        }
    }
}

// ---------------------------------------------------------------------------
// x_dist[n, 0:1024] = hd[3n]*hd[3n+1]; x_dist[n,1024:2048] = hd[3n+1]*hd[3n+2]
// hd/xd always bf16 (ws).
// ---------------------------------------------------------------------------
__global__ __launch_bounds__(256) void pairprod_k(const bf16* __restrict__ hd,
                                                  bf16* __restrict__ xd) {
    const int idx = blockIdx.x * 256 + threadIdx.x;  // 524288 total
    const int n = idx >> 8;
    const int c8 = (idx & 255) << 3;
    const bf16* p;
    if (c8 < 1024) p = hd + (long)(3 * n) * 1024 + c8;
    else           p = hd + (long)(3 * n + 1) * 1024 + (c8 - 1024);
    const bf16* q = p + 1024;
    bf16x8 a = *(const bf16x8*)p, b = *(const bf16x8*)q;
    bf16x8 o;
#pragma unroll
    for (int k = 0; k < 8; ++k) o[k] = (bf16)((float)a[k] * (float)b[k]);
    *(bf16x8*)(xd + (long)n * 2048 + c8) = o;
}

// ---------------------------------------------------------------------------
// out[(g*2048+n)*2+o] = S[g][eid][n][o] + b2[g][eid][o], dtype per flag.
// Eids clamped to [0,E) (defense vs garbage -> OOB NaN reads).
// ---------------------------------------------------------------------------
__global__ __launch_bounds__(256) void finalize_k(const float* __restrict__ S,
        const int* __restrict__ rnn_eid, const int* __restrict__ room_eid,
        const int* __restrict__ dist_eid, const void* __restrict__ b2_rnn,
        const void* __restrict__ b2_room, const void* __restrict__ b2_dist,
        const int* __restrict__ flag, void* __restrict__ out) {
    const int idx = blockIdx.x * 256 + threadIdx.x;
    if (idx >= 12288) return;
    const int dt = *flag;
    const int o = idx & 1;
    const int row = idx >> 1;
    const int g = row >> 11;
    const int n = row & 2047;
    float v;
    if (g == 0) {
        int e = rnn_eid[n]; e = e < 0 ? 0 : (e > 2 ? 2 : e);
        v = S[e * 4096 + n * 2 + o] +
            (dt ? ((const float*)b2_rnn)[e * 2 + o]
                : (float)((const bf16*)b2_rnn)[e * 2 + o]);
    } else if (g == 1) {
        int e = room_eid[n]; e = e < 0 ? 0 : (e > 1 ? 1 : e);
        v = S[12288 + e * 4096 + n * 2 + o] +
            (dt ? ((const float*)b2_room)[e * 2 + o]
                : (float)((const bf16*)b2_room)[e * 2 + o]);
    } else {
        int e = dist_eid[n]; e = e < 0 ? 0 : (e > 1 ? 1 : e);
        v = S[20480 + e * 4096 + n * 2 + o] +
            (dt ? ((const float*)b2_dist)[e * 2 + o]
                : (float)((const bf16*)b2_dist)[e * 2 + o]);
    }
    if (dt) ((float*)out)[idx] = v;
    else    ((bf16*)out)[idx] = (bf16)v;
}

extern "C" void kernel_launch(void* const* d_in, const int* in_sizes, int n_in,
                              void* d_out, int out_size, void* d_ws, size_t ws_size,
                              hipStream_t stream) {
    const void* rnn_feats = d_in[0];
    const void* cube      = d_in[1];
    const void* ego       = d_in[2];
    const int* rnn_eid    = (const int*)d_in[3];
    const int* room_eid   = (const int*)d_in[4];
    const int* dist_eid   = (const int*)d_in[5];
    const void* Wc        = d_in[6];
    const void* bc        = d_in[7];
    const void* Wd        = d_in[8];
    const void* bd        = d_in[9];
    const void* W1_rnn    = d_in[10];
    const void* b1_rnn    = d_in[11];
    const void* W2_rnn    = d_in[12];
    const void* b2_rnn    = d_in[13];
    const void* W1_room   = d_in[14];
    const void* b1_room   = d_in[15];
    const void* W2_room   = d_in[16];
    const void* b2_room   = d_in[17];
    const void* W1_dist   = d_in[18];
    const void* b1_dist   = d_in[19];
    const void* W2_dist   = d_in[20];
    const void* b2_dist   = d_in[21];

    char* ws = (char*)d_ws;
    float* S     = (float*)ws;                    // 28672 fp32 = 114688 B
    int* flag    = (int*)(ws + 114688);           // 4 B (pad to 256)
    bf16* WcT    = (bf16*)(ws + 114944);          // 1024x3200
    bf16* WdT    = (bf16*)(ws + 6668544);         // 1024x3712
    bf16* WrnnT  = (bf16*)(ws + 14270720);        // 3x1024x1024
    bf16* WroomT = (bf16*)(ws + 20562176);        // 2x1024x8192
    bf16* WdistT = (bf16*)(ws + 54116608);        // 2x1024x2048
    bf16* hc     = (bf16*)(ws + 62505216);        // 16384x1024
    bf16* hd     = (bf16*)(ws + 96059648);        // 6144x1024
    bf16* xd     = (bf16*)(ws + 108642560);       // 2048x2048
    // total ws use: 117,031,168 B

    detect_k<<<1, 64, 0, stream>>>((const unsigned*)rnn_feats, flag);
    hipMemsetAsync(S, 0, 114688, stream);

    transpose_k<<<dim3(16, 50, 1),  256, 0, stream>>>(Wc,      WcT,    flag, 3200, 1024);
    transpose_k<<<dim3(16, 58, 1),  256, 0, stream>>>(Wd,      WdT,    flag, 3712, 1024);
    transpose_k<<<dim3(16, 16, 3),  256, 0, stream>>>(W1_rnn,  WrnnT,  flag, 1024, 1024);
    transpose_k<<<dim3(16, 128, 2), 256, 0, stream>>>(W1_room, WroomT, flag, 8192, 1024);
    transpose_k<<<dim3(16, 32, 2),  256, 0, stream>>>(W1_dist, WdistT, flag, 2048, 1024);

    // hc = relu(cube @ Wc + bc)   (16384x1024)
    gemm128<0><<<dim3(8, 128, 1), 256, 0, stream>>>(cube, WcT, bc, nullptr, hc,
                                                    nullptr, flag, 1, 16384, 1024, 3200);
    // hd = relu(ego @ Wd + bd)    (6144x1024)
    gemm128<0><<<dim3(8, 48, 1), 256, 0, stream>>>(ego, WdT, bd, nullptr, hd,
                                                   nullptr, flag, 1, 6144, 1024, 3712);
    pairprod_k<<<2048, 256, 0, stream>>>(hd, xd);

    // expert layer1 + fused layer2 -> S partials
    gemm128<1><<<dim3(8, 16, 3), 256, 0, stream>>>(rnn_feats, WrnnT, b1_rnn,
                                                   W2_rnn, nullptr, S, flag, 1,
                                                   2048, 1024, 1024);
    gemm128<1><<<dim3(8, 16, 2), 256, 0, stream>>>(hc, WroomT, b1_room,
                                                   W2_room, nullptr, S + 12288, flag, 0,
                                                   2048, 1024, 8192);
    gemm128<1><<<dim3(8, 16, 2), 256, 0, stream>>>(xd, WdistT, b1_dist,
                                                   W2_dist, nullptr, S + 20480, flag, 0,
                                                   2048, 1024, 2048);

    finalize_k<<<48, 256, 0, stream>>>(S, rnn_eid, room_eid, dist_eid,
                                       b2_rnn, b2_room, b2_dist, flag, d_out);
}

// Round 4
// 1148.762 us; speedup vs baseline: 1.0421x; 1.0421x over previous
//
#include <hip/hip_runtime.h>

typedef __bf16 bf16;
typedef __bf16 bf16x8 __attribute__((ext_vector_type(8)));
typedef float f32x4 __attribute__((ext_vector_type(4)));

__device__ __forceinline__ void gld_lds16(const bf16* g, bf16* lds_base) {
    __builtin_amdgcn_global_load_lds(
        (const __attribute__((address_space(1))) void*)g,
        (__attribute__((address_space(3))) void*)lds_base, 16, 0, 0);
}

// ---------------------------------------------------------------------------
// Dtype detector: flag=0 if float tensors are bf16, 1 if fp32.
// ---------------------------------------------------------------------------
__global__ void detect_k(const unsigned* __restrict__ rnn, int* __restrict__ flag) {
    const int lane = threadIdx.x;  // 64 threads
    const unsigned w = rnn[lane];
    const int e = (w >> 7) & 0xFF;
    const bool good = (e >= 100 && e <= 130);
    const unsigned long long m = __ballot(good);
    if (lane == 0) *flag = (__popcll(m) >= 48) ? 0 : 1;
}

// ---------------------------------------------------------------------------
// Batched 64x64 tile transpose: in (B,R,C) [dtype per flag] -> out (B,C,R) bf16.
// ---------------------------------------------------------------------------
__global__ __launch_bounds__(256) void transpose_k(const void* __restrict__ in_,
                                                   bf16* __restrict__ out,
                                                   const int* __restrict__ flag,
                                                   int R, int C) {
    __shared__ __align__(16) bf16 t[64][72];
    const int dt = *flag;
    const long boff = (long)blockIdx.z * R * C;
    const int c0 = blockIdx.x * 64, r0 = blockIdx.y * 64;
    const int lr = threadIdx.x >> 2;
    const int lc = (threadIdx.x & 3) * 16;

    bf16x8 v0, v1;
    if (dt) {
        const float* src = (const float*)in_ + boff + (long)(r0 + lr) * C + c0 + lc;
        float4 f0 = ((const float4*)src)[0];
        float4 f1 = ((const float4*)src)[1];
        float4 f2 = ((const float4*)src)[2];
        float4 f3 = ((const float4*)src)[3];
        v0[0]=(bf16)f0.x; v0[1]=(bf16)f0.y; v0[2]=(bf16)f0.z; v0[3]=(bf16)f0.w;
        v0[4]=(bf16)f1.x; v0[5]=(bf16)f1.y; v0[6]=(bf16)f1.z; v0[7]=(bf16)f1.w;
        v1[0]=(bf16)f2.x; v1[1]=(bf16)f2.y; v1[2]=(bf16)f2.z; v1[3]=(bf16)f2.w;
        v1[4]=(bf16)f3.x; v1[5]=(bf16)f3.y; v1[6]=(bf16)f3.z; v1[7]=(bf16)f3.w;
    } else {
        const bf16* src = (const bf16*)in_ + boff + (long)(r0 + lr) * C + c0 + lc;
        v0 = ((const bf16x8*)src)[0];
        v1 = ((const bf16x8*)src)[1];
    }
    *(bf16x8*)(&t[lr][lc])     = v0;
    *(bf16x8*)(&t[lr][lc + 8]) = v1;
    __syncthreads();

    bf16 tmp[16];
#pragma unroll
    for (int k = 0; k < 16; ++k) tmp[k] = t[lc + k][lr];
    bf16* dst = out + boff + (long)(c0 + lr) * R + r0 + lc;
    *(float4*)(dst)     = *(float4*)(&tmp[0]);
    *(float4*)(dst + 8) = *(float4*)(&tmp[8]);
}

// ---------------------------------------------------------------------------
// Shared MFMA helpers: 128x128 tile, BK=64, XOR-swizzled LDS
// (LDS[row][c] = G[row][c^(row&7)], 8-elem chunks). gridDim.x==8 and
// gridDim.y%8==0 required for the XCD swizzle: lin = by*8+bx;
// mb=(lin>>6)*8+(lin&7), nb=(lin>>3)&7 -> the 8 blocks sharing an A-tile
// satisfy lin === mb (mod 8) -> same XCD -> A-tile L2 reuse.
// ---------------------------------------------------------------------------
__device__ __forceinline__ void mfma_tile(const bf16* As, const bf16* Bs,
                                          int wm, int wn, int quad, int l15,
                                          f32x4 acc[4][4]) {
#pragma unroll
    for (int kk = 0; kk < 2; ++kk) {
        bf16x8 af[4], bff[4];
        const int kc = kk * 4 + quad;
#pragma unroll
        for (int i = 0; i < 4; ++i) {
            const int m = wm * 64 + i * 16 + l15;
            af[i] = *(const bf16x8*)(As + m * 64 + (kc ^ (m & 7)) * 8);
            const int n = wn * 64 + i * 16 + l15;
            bff[i] = *(const bf16x8*)(Bs + n * 64 + (kc ^ (n & 7)) * 8);
        }
#pragma unroll
        for (int i = 0; i < 4; ++i)
#pragma unroll
            for (int j = 0; j < 4; ++j)
                acc[i][j] = __builtin_amdgcn_mfma_f32_16x16x32_bf16(
                    af[i], bff[j], acc[i][j], 0, 0, 0);
    }
}

// ---------------------------------------------------------------------------
// Front GEMM: C = bf16(relu(A @ Bt^T + bias)). A (M,K) dtype per flag;
// Bt (N,K) bf16 (ws); bias dtype per flag; C bf16 (ws). grid (8, M/128).
// ---------------------------------------------------------------------------
__global__ __launch_bounds__(256) void gemm_front(const void* __restrict__ A_,
                                                  const bf16* __restrict__ Bt,
                                                  const void* __restrict__ bias_,
                                                  bf16* __restrict__ C,
                                                  const int* __restrict__ flag,
                                                  int M, int N, int K) {
    __shared__ __align__(16) bf16 As[128 * 64];
    __shared__ __align__(16) bf16 Bs[128 * 64];

    const int dt = *flag;
    const long aesz = dt ? 4 : 2;
    const int tid = threadIdx.x, lane = tid & 63, wid = tid >> 6;
    const int wm = wid & 1, wn = wid >> 1;

    const int lin = blockIdx.y * 8 + blockIdx.x;
    const int m0 = ((lin >> 6) * 8 + (lin & 7)) * 128;
    const int n0 = ((lin >> 3) & 7) * 128;

    const int srow = wid * 8 + (lane >> 3);
    const int scol = ((lane & 7) ^ (srow & 7)) * 8;
    const char* Ag = (const char*)A_ + ((long)(m0 + srow) * K + scol) * aesz;
    const bf16* Bg = Bt + (long)(n0 + srow) * K + scol;
    const int ldst = wid * 512 + lane * 8;   // per-lane A ds_write dst (elems)
    const int lbase = wid * 512;             // wave-uniform async dst base

    f32x4 acc[4][4];
#pragma unroll
    for (int i = 0; i < 4; ++i)
#pragma unroll
        for (int j = 0; j < 4; ++j) acc[i][j] = (f32x4){0.f, 0.f, 0.f, 0.f};

    const int quad = lane >> 4, l15 = lane & 15;

    for (int k0 = 0; k0 < K; k0 += 64) {
        bf16x8 av[4];
#pragma unroll
        for (int r = 0; r < 4; ++r) {
            const char* pa = Ag + ((long)(r * 32) * K + k0) * aesz;
            if (dt) {
                float4 f0 = ((const float4*)pa)[0];
                float4 f1 = ((const float4*)pa)[1];
                bf16x8 v;
                v[0]=(bf16)f0.x; v[1]=(bf16)f0.y; v[2]=(bf16)f0.z; v[3]=(bf16)f0.w;
                v[4]=(bf16)f1.x; v[5]=(bf16)f1.y; v[6]=(bf16)f1.z; v[7]=(bf16)f1.w;
                av[r] = v;
            } else {
                av[r] = *(const bf16x8*)pa;
            }
        }
        __syncthreads();
#pragma unroll
        for (int r = 0; r < 4; ++r)
            gld_lds16(Bg + (long)(r * 32) * K + k0, Bs + r * 2048 + lbase);
#pragma unroll
        for (int r = 0; r < 4; ++r)
            *(bf16x8*)(As + r * 2048 + ldst) = av[r];
        __syncthreads();
        mfma_tile(As, Bs, wm, wn, quad, l15, acc);
    }

#pragma unroll
    for (int j = 0; j < 4; ++j) {
        const int colg = n0 + wn * 64 + j * 16 + l15;
        const float bj = dt ? ((const float*)bias_)[colg]
                            : (float)((const bf16*)bias_)[colg];
#pragma unroll
        for (int i = 0; i < 4; ++i) {
            const int rowb = m0 + wm * 64 + i * 16 + quad * 4;
#pragma unroll
            for (int r = 0; r < 4; ++r) {
                float v = acc[i][j][r] + bj;
                v = v > 0.f ? v : 0.f;
                C[(long)(rowb + r) * N + colg] = (bf16)v;
            }
        }
    }
}

// ---------------------------------------------------------------------------
// Combined expert GEMM: all 7 (group,expert) pairs in one launch for
// occupancy (896 blocks vs 256 for room alone). M=2048, N=1024 for all;
// K and A vary per z. Fused layer-2 epilogue:
// atomicAdd S[m][o] += sum_n relu(acc+bias[n]) * W2[n][o].
// ---------------------------------------------------------------------------
struct ExpDescs {
    const void* A[7];
    const bf16* Bt[7];
    const void* biasB[7];
    const void* w2B[7];
    float* S[7];
    long biasEoff[7];
    long w2Eoff[7];
    int K[7];
    int adt[7];   // 1: A has input dtype (per flag); 0: A is ws bf16
};

__global__ __launch_bounds__(256) void gemm_expert(ExpDescs d,
                                                   const int* __restrict__ flag) {
    __shared__ __align__(16) bf16 As[128 * 64];
    __shared__ __align__(16) bf16 Bs[128 * 64];

    const int z = blockIdx.z;
    const int dt = *flag;
    const int adt = d.adt[z] ? dt : 0;
    const long aesz = adt ? 4 : 2;
    const int K = d.K[z];
    const void* A_ = d.A[z];
    const bf16* Bt = d.Bt[z];

    const int tid = threadIdx.x, lane = tid & 63, wid = tid >> 6;
    const int wm = wid & 1, wn = wid >> 1;

    const int lin = blockIdx.y * 8 + blockIdx.x;
    const int m0 = ((lin >> 6) * 8 + (lin & 7)) * 128;
    const int n0 = ((lin >> 3) & 7) * 128;

    const int srow = wid * 8 + (lane >> 3);
    const int scol = ((lane & 7) ^ (srow & 7)) * 8;
    const char* Ag = (const char*)A_ + ((long)(m0 + srow) * K + scol) * aesz;
    const bf16* Agb = (const bf16*)A_ + (long)(m0 + srow) * K + scol;
    const bf16* Bg = Bt + (long)(n0 + srow) * K + scol;
    const int ldst = wid * 512 + lane * 8;
    const int lbase = wid * 512;

    f32x4 acc[4][4];
#pragma unroll
    for (int i = 0; i < 4; ++i)
#pragma unroll
        for (int j = 0; j < 4; ++j) acc[i][j] = (f32x4){0.f, 0.f, 0.f, 0.f};

    const int quad = lane >> 4, l15 = lane & 15;

    if (adt) {  // explicit A staging (fp32 input), async B
        for (int k0 = 0; k0 < K; k0 += 64) {
            bf16x8 av[4];
#pragma unroll
            for (int r = 0; r < 4; ++r) {
                const char* pa = Ag + ((long)(r * 32) * K + k0) * 4;
                float4 f0 = ((const float4*)pa)[0];
                float4 f1 = ((const float4*)pa)[1];
                bf16x8 v;
                v[0]=(bf16)f0.x; v[1]=(bf16)f0.y; v[2]=(bf16)f0.z; v[3]=(bf16)f0.w;
                v[4]=(bf16)f1.x; v[5]=(bf16)f1.y; v[6]=(bf16)f1.z; v[7]=(bf16)f1.w;
                av[r] = v;
            }
            __syncthreads();
#pragma unroll
            for (int r = 0; r < 4; ++r)
                gld_lds16(Bg + (long)(r * 32) * K + k0, Bs + r * 2048 + lbase);
#pragma unroll
            for (int r = 0; r < 4; ++r)
                *(bf16x8*)(As + r * 2048 + ldst) = av[r];
            __syncthreads();
            mfma_tile(As, Bs, wm, wn, quad, l15, acc);
        }
    } else {    // async A and B (both bf16)
        for (int k0 = 0; k0 < K; k0 += 64) {
            __syncthreads();
#pragma unroll
            for (int r = 0; r < 4; ++r) {
                gld_lds16(Agb + (long)(r * 32) * K + k0, As + r * 2048 + lbase);
                gld_lds16(Bg + (long)(r * 32) * K + k0, Bs + r * 2048 + lbase);
            }
            __syncthreads();
            mfma_tile(As, Bs, wm, wn, quad, l15, acc);
        }
    }

    // fused layer-2 epilogue
    const long besz = dt ? 4 : 2;
    const char* bias_b = (const char*)d.biasB[z] + d.biasEoff[z] * besz;
    const char* w2_b   = (const char*)d.w2B[z] + d.w2Eoff[z] * besz;
    float* S = d.S[z];

    float bj[4], w2f[4][2];
#pragma unroll
    for (int j = 0; j < 4; ++j) {
        const int colg = n0 + wn * 64 + j * 16 + l15;
        if (dt) {
            bj[j] = ((const float*)bias_b)[colg];
            w2f[j][0] = ((const float*)w2_b)[colg * 2 + 0];
            w2f[j][1] = ((const float*)w2_b)[colg * 2 + 1];
        } else {
            bj[j] = (float)((const bf16*)bias_b)[colg];
            w2f[j][0] = (float)((const bf16*)w2_b)[colg * 2 + 0];
            w2f[j][1] = (float)((const bf16*)w2_b)[colg * 2 + 1];
        }
    }
#pragma unroll
    for (int i = 0; i < 4; ++i) {
#pragma unroll
        for (int r = 0; r < 4; ++r) {
            float s0 = 0.f, s1 = 0.f;
#pragma unroll
            for (int j = 0; j < 4; ++j) {
                float h = acc[i][j][r] + bj[j];
                h = h > 0.f ? h : 0.f;
                s0 += h * w2f[j][0];
                s1 += h * w2f[j][1];
            }
#pragma unroll
            for (int msk = 1; msk < 16; msk <<= 1) {
                s0 += __shfl_xor(s0, msk);
                s1 += __shfl_xor(s1, msk);
            }
            if (l15 == 0) {
                const int rowg = m0 + wm * 64 + i * 16 + quad * 4 + r;
                atomicAdd(&S[rowg * 2 + 0], s0);
                atomicAdd(&S[rowg * 2 + 1], s1);
            }
        }
    }
}

// ---------------------------------------------------------------------------
// x_dist[n,0:1024] = hd[3n]*hd[3n+1]; x_dist[n,1024:2048] = hd[3n+1]*hd[3n+2]
// ---------------------------------------------------------------------------
__global__ __launch_bounds__(256) void pairprod_k(const bf16* __restrict__ hd,
                                                  bf16* __restrict__ xd) {
    const int idx = blockIdx.x * 256 + threadIdx.x;  // 524288 total
    const int n = idx >> 8;
    const int c8 = (idx & 255) << 3;
    const bf16* p;
    if (c8 < 1024) p = hd + (long)(3 * n) * 1024 + c8;
    else           p = hd + (long)(3 * n + 1) * 1024 + (c8 - 1024);
    const bf16* q = p + 1024;
    bf16x8 a = *(const bf16x8*)p, b = *(const bf16x8*)q;
    bf16x8 o;
#pragma unroll
    for (int k = 0; k < 8; ++k) o[k] = (bf16)((float)a[k] * (float)b[k]);
    *(bf16x8*)(xd + (long)n * 2048 + c8) = o;
}

// ---------------------------------------------------------------------------
// out[(g*2048+n)*2+o] = S[g][eid][n][o] + b2[g][eid][o], dtype per flag.
// ---------------------------------------------------------------------------
__global__ __launch_bounds__(256) void finalize_k(const float* __restrict__ S,
        const int* __restrict__ rnn_eid, const int* __restrict__ room_eid,
        const int* __restrict__ dist_eid, const void* __restrict__ b2_rnn,
        const void* __restrict__ b2_room, const void* __restrict__ b2_dist,
        const int* __restrict__ flag, void* __restrict__ out) {
    const int idx = blockIdx.x * 256 + threadIdx.x;
    if (idx >= 12288) return;
    const int dt = *flag;
    const int o = idx & 1;
    const int row = idx >> 1;
    const int g = row >> 11;
    const int n = row & 2047;
    float v;
    if (g == 0) {
        int e = rnn_eid[n]; e = e < 0 ? 0 : (e > 2 ? 2 : e);
        v = S[e * 4096 + n * 2 + o] +
            (dt ? ((const float*)b2_rnn)[e * 2 + o]
                : (float)((const bf16*)b2_rnn)[e * 2 + o]);
    } else if (g == 1) {
        int e = room_eid[n]; e = e < 0 ? 0 : (e > 1 ? 1 : e);
        v = S[12288 + e * 4096 + n * 2 + o] +
            (dt ? ((const float*)b2_room)[e * 2 + o]
                : (float)((const bf16*)b2_room)[e * 2 + o]);
    } else {
        int e = dist_eid[n]; e = e < 0 ? 0 : (e > 1 ? 1 : e);
        v = S[20480 + e * 4096 + n * 2 + o] +
            (dt ? ((const float*)b2_dist)[e * 2 + o]
                : (float)((const bf16*)b2_dist)[e * 2 + o]);
    }
    if (dt) ((float*)out)[idx] = v;
    else    ((bf16*)out)[idx] = (bf16)v;
}

extern "C" void kernel_launch(void* const* d_in, const int* in_sizes, int n_in,
                              void* d_out, int out_size, void* d_ws, size_t ws_size,
                              hipStream_t stream) {
    const void* rnn_feats = d_in[0];
    const void* cube      = d_in[1];
    const void* ego       = d_in[2];
    const int* rnn_eid    = (const int*)d_in[3];
    const int* room_eid   = (const int*)d_in[4];
    const int* dist_eid   = (const int*)d_in[5];
    const void* Wc        = d_in[6];
    const void* bc        = d_in[7];
    const void* Wd        = d_in[8];
    const void* bd        = d_in[9];
    const void* W1_rnn    = d_in[10];
    const void* b1_rnn    = d_in[11];
    const void* W2_rnn    = d_in[12];
    const void* b2_rnn    = d_in[13];
    const void* W1_room   = d_in[14];
    const void* b1_room   = d_in[15];
    const void* W2_room   = d_in[16];
    const void* b2_room   = d_in[17];
    const void* W1_dist   = d_in[18];
    const void* b1_dist   = d_in[19];
    const void* W2_dist   = d_in[20];
    const void* b2_dist   = d_in[21];

    char* ws = (char*)d_ws;
    float* S     = (float*)ws;                    // 28672 fp32 = 114688 B
    int* flag    = (int*)(ws + 114688);           // 4 B (pad to 256)
    bf16* WcT    = (bf16*)(ws + 114944);          // 1024x3200
    bf16* WdT    = (bf16*)(ws + 6668544);         // 1024x3712
    bf16* WrnnT  = (bf16*)(ws + 14270720);        // 3x1024x1024
    bf16* WroomT = (bf16*)(ws + 20562176);        // 2x1024x8192
    bf16* WdistT = (bf16*)(ws + 54116608);        // 2x1024x2048
    bf16* hc     = (bf16*)(ws + 62505216);        // 16384x1024
    bf16* hd     = (bf16*)(ws + 96059648);        // 6144x1024
    bf16* xd     = (bf16*)(ws + 108642560);       // 2048x2048

    detect_k<<<1, 64, 0, stream>>>((const unsigned*)rnn_feats, flag);
    hipMemsetAsync(S, 0, 114688, stream);

    transpose_k<<<dim3(16, 50, 1),  256, 0, stream>>>(Wc,      WcT,    flag, 3200, 1024);
    transpose_k<<<dim3(16, 58, 1),  256, 0, stream>>>(Wd,      WdT,    flag, 3712, 1024);
    transpose_k<<<dim3(16, 16, 3),  256, 0, stream>>>(W1_rnn,  WrnnT,  flag, 1024, 1024);
    transpose_k<<<dim3(16, 128, 2), 256, 0, stream>>>(W1_room, WroomT, flag, 8192, 1024);
    transpose_k<<<dim3(16, 32, 2),  256, 0, stream>>>(W1_dist, WdistT, flag, 2048, 1024);

    // hc = relu(cube @ Wc + bc)   (16384x1024)
    gemm_front<<<dim3(8, 128), 256, 0, stream>>>(cube, WcT, bc, hc, flag,
                                                 16384, 1024, 3200);
    // hd = relu(ego @ Wd + bd)    (6144x1024)
    gemm_front<<<dim3(8, 48), 256, 0, stream>>>(ego, WdT, bd, hd, flag,
                                                6144, 1024, 3712);
    pairprod_k<<<2048, 256, 0, stream>>>(hd, xd);

    // all 7 expert GEMMs (layer1 + fused layer2 -> S) in one launch
    ExpDescs D;
    for (int e = 0; e < 3; ++e) {
        D.A[e] = rnn_feats;            D.Bt[e] = WrnnT + (long)e * 1024 * 1024;
        D.biasB[e] = b1_rnn;           D.biasEoff[e] = (long)e * 1024;
        D.w2B[e] = W2_rnn;             D.w2Eoff[e] = (long)e * 2048;
        D.S[e] = S + e * 4096;         D.K[e] = 1024;  D.adt[e] = 1;
    }
    for (int e = 0; e < 2; ++e) {
        const int z = 3 + e;
        D.A[z] = hc;                   D.Bt[z] = WroomT + (long)e * 1024 * 8192;
        D.biasB[z] = b1_room;          D.biasEoff[z] = (long)e * 1024;
        D.w2B[z] = W2_room;            D.w2Eoff[z] = (long)e * 2048;
        D.S[z] = S + 12288 + e * 4096; D.K[z] = 8192;  D.adt[z] = 0;
    }
    for (int e = 0; e < 2; ++e) {
        const int z = 5 + e;
        D.A[z] = xd;                   D.Bt[z] = WdistT + (long)e * 1024 * 2048;
        D.biasB[z] = b1_dist;          D.biasEoff[z] = (long)e * 1024;
        D.w2B[z] = W2_dist;            D.w2Eoff[z] = (long)e * 2048;
        D.S[z] = S + 20480 + e * 4096; D.K[z] = 2048;  D.adt[z] = 0;
    }
    gemm_expert<<<dim3(8, 16, 7), 256, 0, stream>>>(D, flag);

    finalize_k<<<48, 256, 0, stream>>>(S, rnn_eid, room_eid, dist_eid,
                                       b2_rnn, b2_room, b2_dist, flag, d_out);
}